// Round 7
// baseline (395.473 us; speedup 1.0000x reference)
//
#include <hip/hip_runtime.h>

// DiscreteKeyValueBottleneck on MI355X (gfx950)
// B=4 T=1024 H=12 C=4096 DK=DV=64, N=B*T=4096, DIM=768
//
// Pipeline (absmax=0 since round 3): split-bf16 MFMA scores (xh*eh + xh*el +
// xl*eh), top-2 margin filter (TAU), numpy-bit-exact fp32 re-argmin of
// flagged queries. Round 7: barrier-free pass-1 (each wave loads its own B
// fragments straight from L2 via contiguous 1KB dwordx4, register
// double-buffered; no LDS staging, no __syncthreads in the K-loop), MFMA
// dependency chain split in two, 128-thread blocks (2 waves = 2 code halves,
// 32 queries) at 6 blocks/CU, recheck fused into the epilogue (3rd kernel and
// its launch gap removed).

#define HEADS 12
#define CODES 4096
#define DKI   64
#define DVI   64
#define NTOK  4096
#define DIMX  768
#define TAU   5e-5f

typedef short bf16x8 __attribute__((ext_vector_type(8)));
typedef float f32x16 __attribute__((ext_vector_type(16)));

__device__ __forceinline__ unsigned short f2bf(float f) {   // RNE
    unsigned int u = __float_as_uint(f);
    return (unsigned short)((u + 0x7fff + ((u >> 16) & 1)) >> 16);
}
__device__ __forceinline__ float bf2f(unsigned short h) {
    return __uint_as_float(((unsigned int)h) << 16);
}

// ---------------- numpy bit-exact helpers (fp32, contraction OFF) -----------
__device__ __forceinline__ float np_sumsq64(const float* __restrict__ a) {
#pragma clang fp contract(off)
    float r[8];
#pragma unroll
    for (int j = 0; j < 8; ++j) r[j] = a[j] * a[j];
#pragma unroll
    for (int i = 8; i < 64; i += 8)
#pragma unroll
        for (int j = 0; j < 8; ++j) r[j] += a[i + j] * a[i + j];
    return ((r[0] + r[1]) + (r[2] + r[3])) + ((r[4] + r[5]) + (r[6] + r[7]));
}

__device__ __forceinline__ float np_dot64(const float* __restrict__ xx,
                                          const float* __restrict__ ee) {
#pragma clang fp contract(off)
    float S0 = 0.f, S1 = 0.f, S2 = 0.f, S3 = 0.f;
#pragma unroll
    for (int t = 0; t < 64; t += 16) {
        float p[16];
#pragma unroll
        for (int j = 0; j < 16; ++j) p[j] = xx[t + j] * ee[t + j];
        S0 = p[0] + (p[4] + (p[8]  + (p[12] + S0)));
        S1 = p[1] + (p[5] + (p[9]  + (p[13] + S1)));
        S2 = p[2] + (p[6] + (p[10] + (p[14] + S2)));
        S3 = p[3] + (p[7] + (p[11] + (p[15] + S3)));
    }
    return (S0 + S1) + (S2 + S3);
}

// ---- prep: np-exact e2; E2T transposed chunk layout ------------------------
// E2T per (h, 32-code chunk): 8KB block = [hi: piece p(0..7) x 32 codes x 16B]
// [lo: same]. piece p holds dims p*8..p*8+7. 16B-unit index:
//   (h*128+ch)*512 + (lo?256:0) + p*32 + (c&31)
__global__ __launch_bounds__(256) void prep_ke(const float* __restrict__ ke,
                                               uint4* __restrict__ E2T,
                                               float* __restrict__ e2np,
                                               float* __restrict__ m2half) {
    int idx = blockIdx.x * 256 + threadIdx.x;
    if (idx >= HEADS * CODES) return;
    float er[DKI];
    const float4* p4 = reinterpret_cast<const float4*>(ke + (size_t)idx * DKI);
#pragma unroll
    for (int i = 0; i < DKI / 4; ++i) {
        float4 v = p4[i];
        er[i * 4 + 0] = v.x; er[i * 4 + 1] = v.y;
        er[i * 4 + 2] = v.z; er[i * 4 + 3] = v.w;
    }
    float e2 = np_sumsq64(er);
    e2np[idx]   = e2;
    m2half[idx] = -0.5f * e2;

    int h = idx >> 12, c = idx & 4095, ch = c >> 5, cc = c & 31;
    size_t base = (size_t)(h * 128 + ch) * 512 + cc;
#pragma unroll
    for (int p = 0; p < 8; ++p) {
        unsigned int hb[8], lb[8];
#pragma unroll
        for (int j = 0; j < 8; ++j) {
            float f = er[p * 8 + j];
            unsigned short hh = f2bf(f);
            hb[j] = hh;
            lb[j] = f2bf(f - bf2f(hh));
        }
        uint4 hv, lv;
        hv.x = hb[0] | (hb[1] << 16); hv.y = hb[2] | (hb[3] << 16);
        hv.z = hb[4] | (hb[5] << 16); hv.w = hb[6] | (hb[7] << 16);
        lv.x = lb[0] | (lb[1] << 16); lv.y = lb[2] | (lb[3] << 16);
        lv.z = lb[4] | (lb[5] << 16); lv.w = lb[6] | (lb[7] << 16);
        E2T[base + p * 32]       = hv;
        E2T[base + 256 + p * 32] = lv;
    }
}

// ---- fused pass: barrier-free MFMA scan + margin filter + inline recheck ---
// 128 threads = 2 waves; wave w scans code half [w*2048, w*2048+2048) for the
// block's 32 queries. No __syncthreads until the epilogue.
__global__ __launch_bounds__(128, 3) void dkvb_mfma(const float* __restrict__ x,
                                                    const char* __restrict__ E2T,
                                                    const float* __restrict__ ke,
                                                    const float* __restrict__ values,
                                                    const float* __restrict__ m2half,
                                                    const float* __restrict__ e2np,
                                                    float* __restrict__ out) {
    __shared__ float sbv[2][32], sbv2[2][32];
    __shared__ int   sbi[2][32];
    __shared__ int   fin[32];
    __shared__ float xs[DKI];
    __shared__ int   flagq[32];
    __shared__ int   nf;
    __shared__ float rwv[2];
    __shared__ int   rwi[2];
    __shared__ int   bcst;

    const int tid  = threadIdx.x;
    const int b    = blockIdx.x;
    const int h    = b % 12;            // XCD-friendly head pinning
    const int q0   = (b / 12) * 32;     // token-tile base
    const int w    = tid >> 6;          // wave = code half
    const int lane = tid & 63;
    const int col  = lane & 31;         // A row m / B col n / D col
    const int kh   = lane >> 5;         // k-half within each K=16 step
    const int cbase = w * 2048;

    if (tid == 0) nf = 0;

    // ---- A fragments: query q0+col; step t: k = t*16 + kh*8 + j ------------
    const float* xrow = x + (size_t)(q0 + col) * DIMX + h * DKI;
    bf16x8 ah[4], al[4];
#pragma unroll
    for (int t = 0; t < 4; ++t) {
        const float* p = xrow + t * 16 + kh * 8;
        bf16x8 hi, lo;
#pragma unroll
        for (int j = 0; j < 8; ++j) {
            float f = p[j];
            unsigned short hb = f2bf(f);
            hi[j] = (short)hb;
            lo[j] = (short)f2bf(f - bf2f(hb));
        }
        ah[t] = hi; al[t] = lo;
    }

    // ---- B source: contiguous 1KB per load group ---------------------------
    // chunk i hi piece for step t: gbase + i*8192 + t*1024 + lane*16 ; lo +4096
    const char* gbase = E2T + (size_t)(h * 128 + w * 64) * 8192 + lane * 16;
    const float* m2p  = m2half + h * CODES + cbase + col;

    float bv[16], bv2[16]; int bi[16];
#pragma unroll
    for (int r = 0; r < 16; ++r) { bv[r] = -1e30f; bv2[r] = -1e30f; bi[r] = 0; }

    // preload chunk 0 + m2
    bf16x8 Bh[2][4], Bl[2][4];
#pragma unroll
    for (int t = 0; t < 4; ++t) {
        Bh[0][t] = *reinterpret_cast<const bf16x8*>(gbase + t * 1024);
        Bl[0][t] = *reinterpret_cast<const bf16x8*>(gbase + 4096 + t * 1024);
    }
    float m2c = m2p[0];

#pragma unroll 2
    for (int i = 0; i < 64; ++i) {
        const int cur = i & 1, nxt = cur ^ 1;
        const int ip  = (i + 1 < 64) ? i + 1 : 63;     // tail refetch, harmless
        const char* g = gbase + (size_t)ip * 8192;
#pragma unroll
        for (int t = 0; t < 4; ++t) {
            Bh[nxt][t] = *reinterpret_cast<const bf16x8*>(g + t * 1024);
            Bl[nxt][t] = *reinterpret_cast<const bf16x8*>(g + 4096 + t * 1024);
        }
        float m2n = m2p[ip * 32];

        f32x16 a1, a2;
#pragma unroll
        for (int r = 0; r < 16; ++r) { a1[r] = m2c; a2[r] = 0.f; }

        // two independent chains: a1 = hh+lh (depth 8), a2 = hl (depth 4)
        a1 = __builtin_amdgcn_mfma_f32_32x32x16_bf16(ah[0], Bh[cur][0], a1, 0, 0, 0);
        a2 = __builtin_amdgcn_mfma_f32_32x32x16_bf16(ah[0], Bl[cur][0], a2, 0, 0, 0);
        a1 = __builtin_amdgcn_mfma_f32_32x32x16_bf16(ah[1], Bh[cur][1], a1, 0, 0, 0);
        a2 = __builtin_amdgcn_mfma_f32_32x32x16_bf16(ah[1], Bl[cur][1], a2, 0, 0, 0);
        a1 = __builtin_amdgcn_mfma_f32_32x32x16_bf16(ah[2], Bh[cur][2], a1, 0, 0, 0);
        a2 = __builtin_amdgcn_mfma_f32_32x32x16_bf16(ah[2], Bl[cur][2], a2, 0, 0, 0);
        a1 = __builtin_amdgcn_mfma_f32_32x32x16_bf16(ah[3], Bh[cur][3], a1, 0, 0, 0);
        a2 = __builtin_amdgcn_mfma_f32_32x32x16_bf16(ah[3], Bl[cur][3], a2, 0, 0, 0);
        a1 = __builtin_amdgcn_mfma_f32_32x32x16_bf16(al[0], Bh[cur][0], a1, 0, 0, 0);
        a1 = __builtin_amdgcn_mfma_f32_32x32x16_bf16(al[1], Bh[cur][1], a1, 0, 0, 0);
        a1 = __builtin_amdgcn_mfma_f32_32x32x16_bf16(al[2], Bh[cur][2], a1, 0, 0, 0);
        a1 = __builtin_amdgcn_mfma_f32_32x32x16_bf16(al[3], Bh[cur][3], a1, 0, 0, 0);

        int cc = cbase + i * 32 + col;
#pragma unroll
        for (int r = 0; r < 16; ++r) {
            float s = a1[r] + a2[r];
            bv2[r] = __builtin_amdgcn_fmed3f(bv2[r], s, bv[r]);
            bool gt = s > bv[r];
            bi[r] = gt ? cc : bi[r];
            bv[r] = fmaxf(bv[r], s);
        }
        m2c = m2n;
    }

    // ---- cross-col top-2 butterfly (32 cols; masks 1..16) ------------------
#pragma unroll
    for (int r = 0; r < 16; ++r) {
#pragma unroll
        for (int m = 1; m <= 16; m <<= 1) {
            float pv1 = __shfl_xor(bv[r],  m, 64);
            float pv2 = __shfl_xor(bv2[r], m, 64);
            int   pi  = __shfl_xor(bi[r],  m, 64);
            bool take = (pv1 > bv[r]) || (pv1 == bv[r] && pi < bi[r]);
            float lo1 = take ? bv[r] : pv1;
            bv2[r] = fmaxf(lo1, fmaxf(bv2[r], pv2));
            bv[r]  = take ? pv1 : bv[r];
            bi[r]  = take ? pi  : bi[r];
        }
    }
    if (col == 0) {                     // lanes 0 and 32
#pragma unroll
        for (int r = 0; r < 16; ++r) {
            int row = (r & 3) + 8 * (r >> 2) + 4 * kh;   // D-row = query
            sbv [w][row] = bv[r];
            sbv2[w][row] = bv2[r];
            sbi [w][row] = bi[r];
        }
    }
    __syncthreads();

    // ---- merge halves, flag small margins ----------------------------------
    if (tid < 32) {
        int q = tid;
        float bvA = sbv[0][q],  bvB = sbv[1][q];
        float b2A = sbv2[0][q], b2B = sbv2[1][q];
        bool  tb  = bvB > bvA;                    // tie -> half 0 (smaller c)
        float bvm  = tb ? bvB : bvA;
        int   bim  = tb ? sbi[1][q] : sbi[0][q];
        float bv2m = fmaxf(fmaxf(b2A, b2B), fminf(bvA, bvB));
        fin[q] = bim;
        if (bvm - bv2m < TAU) {
            int slot = atomicAdd(&nf, 1);
            flagq[slot] = q;
        }
    }
    __syncthreads();

    // ---- gather values[h, fin[q], :] -> out; 32 rows x 16 float4 -----------
#pragma unroll
    for (int k = 0; k < 4; ++k) {
        int f   = tid + k * 128;
        int row = f >> 4;
        int cl  = (f & 15) << 2;
        int idx = fin[row];
        float4 v = *reinterpret_cast<const float4*>(
            values + (size_t)h * CODES * DVI + (size_t)idx * DVI + cl);
        *reinterpret_cast<float4*>(
            out + (size_t)(q0 + row) * DIMX + h * DVI + cl) = v;
    }

    // ---- inline numpy-bit-exact recheck for flagged queries ----------------
    int cnt = nf;                                  // valid: barrier above
    for (int f = 0; f < cnt; ++f) {
        int q = flagq[f];
        int n = q0 + q;
        if (tid < DKI) xs[tid] = x[(size_t)n * DIMX + h * DKI + tid];
        __syncthreads();

        float x2 = np_sumsq64(xs);
        float best = 3.4e38f; int bestc = 0x7fffffff;
#pragma unroll 1
        for (int it = 0; it < 32; ++it) {
            int c = it * 128 + tid;                // ascending per thread
            float er[DKI];
            const float4* p = reinterpret_cast<const float4*>(
                ke + ((size_t)h * CODES + c) * DKI);
#pragma unroll
            for (int i = 0; i < DKI / 4; ++i) {
                float4 v = p[i];
                er[i * 4 + 0] = v.x; er[i * 4 + 1] = v.y;
                er[i * 4 + 2] = v.z; er[i * 4 + 3] = v.w;
            }
            float dot = np_dot64(xs, er);
            float d2;
            {
#pragma clang fp contract(off)
                d2 = (x2 - 2.0f * dot) + e2np[h * CODES + c];
            }
            if (d2 < best) { best = d2; bestc = c; }
        }
#pragma unroll
        for (int m = 1; m <= 32; m <<= 1) {
            float pv = __shfl_xor(best, m, 64);
            int   pi = __shfl_xor(bestc, m, 64);
            if (pv < best || (pv == best && pi < bestc)) { best = pv; bestc = pi; }
        }
        if (lane == 0) { rwv[w] = best; rwi[w] = bestc; }
        __syncthreads();
        if (tid == 0) {
            bcst = (rwv[1] < rwv[0] || (rwv[1] == rwv[0] && rwi[1] < rwi[0]))
                   ? rwi[1] : rwi[0];
        }
        __syncthreads();
        int c = bcst;
        if (tid < DVI)
            out[(size_t)n * DIMX + h * DVI + tid] =
                values[((size_t)h * CODES + c) * DVI + tid];
        __syncthreads();                           // xs reuse
    }
}

extern "C" void kernel_launch(void* const* d_in, const int* in_sizes, int n_in,
                              void* d_out, int out_size, void* d_ws, size_t ws_size,
                              hipStream_t stream) {
    const float* x      = (const float*)d_in[0];
    // d_in[1] = mask (all ones; unused)
    const float* ke     = (const float*)d_in[2];
    const float* values = (const float*)d_in[3];
    // d_in[4] = key_optim (unused)
    float* out = (float*)d_out;

    char* ws = (char*)d_ws;
    float* e2np   = (float*)ws;  ws += HEADS * CODES * sizeof(float);
    float* m2half = (float*)ws;  ws += HEADS * CODES * sizeof(float);
    char*  E2T    = ws;          // HEADS*CODES*DKI*2*2 bytes = 12.6 MB

    prep_ke<<<dim3((HEADS * CODES + 255) / 256), dim3(256), 0, stream>>>(
        ke, (uint4*)E2T, e2np, m2half);
    dkvb_mfma<<<dim3((NTOK / 32) * HEADS), dim3(128), 0, stream>>>(
        x, E2T, ke, values, m2half, e2np, out);
}

// Round 10
// 280.007 us; speedup vs baseline: 1.4124x; 1.4124x over previous
//
#include <hip/hip_runtime.h>

// DiscreteKeyValueBottleneck on MI355X (gfx950)
// B=4 T=1024 H=12 C=4096 DK=DV=64, N=B*T=4096, DIM=768
//
// Pipeline (absmax=0 rounds 3-7): split-bf16 MFMA scores (xh*eh + xh*el +
// xl*eh), top-2 margin filter (TAU), numpy-bit-exact fp32 re-argmin of
// flagged queries. Round 10: r9 closed the RAW race (vmcnt(9) group
// discipline) but left the WAR race: the machine scheduler could hoist the
// chunk-(i+2) global_load_lds above chunk-i's ds_reads (no modeled
// dependency), and a descheduled wave let the DMA data land before the
// ds_read executed. Fix: a second full barrier inside the body --
// `s_waitcnt lgkmcnt(0)` + memory clobber AFTER the ds_reads, BEFORE the
// prefetch: ds_read data is in VGPRs before any overwriting load is issued.
// K-loop remains __syncthreads-free (wave-private buffers).

#define HEADS 12
#define CODES 4096
#define DKI   64
#define DVI   64
#define NTOK  4096
#define DIMX  768
#define TAU   5e-5f
#define WLCAP 32768
#define CHB   8448            // staged chunk bytes: 4096 hi + 4096 lo + 256 m2

typedef short bf16x8 __attribute__((ext_vector_type(8)));
typedef float f32x16 __attribute__((ext_vector_type(16)));
typedef unsigned long long u64;

__device__ __forceinline__ unsigned short f2bf(float f) {   // RNE
    unsigned int u = __float_as_uint(f);
    return (unsigned short)((u + 0x7fff + ((u >> 16) & 1)) >> 16);
}
__device__ __forceinline__ float bf2f(unsigned short h) {
    return __uint_as_float(((unsigned int)h) << 16);
}
__device__ __forceinline__ void async_load16(const void* g, void* l) {
    __builtin_amdgcn_global_load_lds(
        (const __attribute__((address_space(1))) unsigned int*)g,
        (__attribute__((address_space(3))) unsigned int*)l, 16, 0, 0);
}
__device__ __forceinline__ void async_load4(const void* g, void* l) {
    __builtin_amdgcn_global_load_lds(
        (const __attribute__((address_space(1))) unsigned int*)g,
        (__attribute__((address_space(3))) unsigned int*)l, 4, 0, 0);
}

// ---------------- numpy bit-exact helpers (fp32, contraction OFF) -----------
__device__ __forceinline__ float np_sumsq64(const float* __restrict__ a) {
#pragma clang fp contract(off)
    float r[8];
#pragma unroll
    for (int j = 0; j < 8; ++j) r[j] = a[j] * a[j];
#pragma unroll
    for (int i = 8; i < 64; i += 8)
#pragma unroll
        for (int j = 0; j < 8; ++j) r[j] += a[i + j] * a[i + j];
    return ((r[0] + r[1]) + (r[2] + r[3])) + ((r[4] + r[5]) + (r[6] + r[7]));
}

__device__ __forceinline__ float np_dot64(const float* __restrict__ xx,
                                          const float* __restrict__ ee) {
#pragma clang fp contract(off)
    float S0 = 0.f, S1 = 0.f, S2 = 0.f, S3 = 0.f;
#pragma unroll
    for (int t = 0; t < 64; t += 16) {
        float p[16];
#pragma unroll
        for (int j = 0; j < 16; ++j) p[j] = xx[t + j] * ee[t + j];
        S0 = p[0] + (p[4] + (p[8]  + (p[12] + S0)));
        S1 = p[1] + (p[5] + (p[9]  + (p[13] + S1)));
        S2 = p[2] + (p[6] + (p[10] + (p[14] + S2)));
        S3 = p[3] + (p[7] + (p[11] + (p[15] + S3)));
    }
    return (S0 + S1) + (S2 + S3);
}

// ---- prep: np-exact e2; E2T chunk layout + embedded m2 ---------------------
// Per (h, 32-code chunk), 8448B: [hi: piece p(0..7) x 32 codes x 16B]
// [lo: same] [m2: 32 floats = -0.5*e2] [pad 128B]. piece p = dims p*8..p*8+7.
__global__ __launch_bounds__(256) void prep_ke(const float* __restrict__ ke,
                                               char* __restrict__ E2T,
                                               float* __restrict__ e2np,
                                               int* __restrict__ wl_count) {
    if (blockIdx.x == 0 && threadIdx.x == 0) *wl_count = 0;
    int idx = blockIdx.x * 256 + threadIdx.x;
    if (idx >= HEADS * CODES) return;
    float er[DKI];
    const float4* p4 = reinterpret_cast<const float4*>(ke + (size_t)idx * DKI);
#pragma unroll
    for (int i = 0; i < DKI / 4; ++i) {
        float4 v = p4[i];
        er[i * 4 + 0] = v.x; er[i * 4 + 1] = v.y;
        er[i * 4 + 2] = v.z; er[i * 4 + 3] = v.w;
    }
    float e2 = np_sumsq64(er);
    e2np[idx] = e2;

    int h = idx >> 12, c = idx & 4095, ch = c >> 5, cc = c & 31;
    char* cb = E2T + (size_t)(h * 128 + ch) * CHB;
    uint4* hq = reinterpret_cast<uint4*>(cb);
    uint4* lq = reinterpret_cast<uint4*>(cb + 4096);
#pragma unroll
    for (int p = 0; p < 8; ++p) {
        unsigned int hb[8], lb[8];
#pragma unroll
        for (int j = 0; j < 8; ++j) {
            float f = er[p * 8 + j];
            unsigned short hh = f2bf(f);
            hb[j] = hh;
            lb[j] = f2bf(f - bf2f(hh));
        }
        uint4 hv, lv;
        hv.x = hb[0] | (hb[1] << 16); hv.y = hb[2] | (hb[3] << 16);
        hv.z = hb[4] | (hb[5] << 16); hv.w = hb[6] | (hb[7] << 16);
        lv.x = lb[0] | (lb[1] << 16); lv.y = lb[2] | (lb[3] << 16);
        lv.z = lb[4] | (lb[5] << 16); lv.w = lb[6] | (lb[7] << 16);
        hq[p * 32 + cc] = hv;
        lq[p * 32 + cc] = lv;
    }
    reinterpret_cast<float*>(cb + 8192)[cc] = -0.5f * e2;
}

// ---- pass 1: wave-private LDS staging, barrier-free, explicit waitcnts -----
__global__ __launch_bounds__(128, 2) void dkvb_mfma(const float* __restrict__ x,
                                                    const char* __restrict__ E2T,
                                                    const float* __restrict__ values,
                                                    int* __restrict__ wl_count,
                                                    int* __restrict__ wl,
                                                    u64* __restrict__ packed,
                                                    float* __restrict__ out) {
    __shared__ __align__(16) char lds[2][2][CHB];   // [dbuf][wave][chunk]
    __shared__ float sbv[2][32], sbv2[2][32];
    __shared__ int   sbi[2][32];
    __shared__ int   fin[32];

    const int tid  = threadIdx.x;
    const int b    = blockIdx.x;
    const int h    = b % 12;            // XCD-friendly head pinning
    const int q0   = (b / 12) * 32;
    const int w    = tid >> 6;          // wave = code half
    const int lane = tid & 63;
    const int col  = lane & 31;         // A row m / B col n / D col
    const int kh   = lane >> 5;         // k-half within each K=16 step
    const int cbase = w * 2048;

    // ---- A fragments: query q0+col; step t: k = t*16 + kh*8 + j ------------
    const float* xrow = x + (size_t)(q0 + col) * DIMX + h * DKI;
    bf16x8 ah[4], al[4];
#pragma unroll
    for (int t = 0; t < 4; ++t) {
        const float* p = xrow + t * 16 + kh * 8;
        bf16x8 hi, lo;
#pragma unroll
        for (int j = 0; j < 8; ++j) {
            float f = p[j];
            unsigned short hb = f2bf(f);
            hi[j] = (short)hb;
            lo[j] = (short)f2bf(f - bf2f(hb));
        }
        ah[t] = hi; al[t] = lo;
    }

    // wave-uniform chunk base for this wave's code half
    const char* gsrc0 = E2T + (size_t)(h * 128 + w * 64) * CHB;

    float bv[16], bv2[16]; int bi[16];
#pragma unroll
    for (int r = 0; r < 16; ++r) { bv[r] = -1e30f; bv2[r] = -1e30f; bi[r] = 0; }

    // one staging group = exactly 9 global_load_lds ops (8 w16 + 1 w4)
    auto stage = [&](const char* cb, char* buf) {
#pragma unroll
        for (int k = 0; k < 8; ++k)
            async_load16(cb + k * 1024 + lane * 16, buf + k * 1024);
        async_load4(cb + 8192 + lane * 4, buf + 8192);
    };

    // preload chunks 0,1
    stage(gsrc0,        &lds[0][w][0]);
    stage(gsrc0 + CHB,  &lds[1][w][0]);

    auto body = [&](char* buf, int i) {
        // RAW: chunk i landed when <=9 vmem outstanding (chunk i+1's group).
        asm volatile("s_waitcnt vmcnt(9)" ::: "memory");

        float m2v = *reinterpret_cast<const float*>(buf + 8192 + col * 4);
        bf16x8 Bh[4], Bl[4];
#pragma unroll
        for (int t = 0; t < 4; ++t) {
            int off = ((2 * t + kh) * 32 + col) * 16;
            Bh[t] = *reinterpret_cast<const bf16x8*>(buf + off);
            Bl[t] = *reinterpret_cast<const bf16x8*>(buf + 4096 + off);
        }
        // WAR: ds_read data must be IN VGPRS before the overwriting prefetch
        // is issued (asm = full sched barrier; lgkmcnt(0) = reads returned).
        asm volatile("s_waitcnt lgkmcnt(0)" ::: "memory");

        // prefetch chunk i+2 into this buffer (flight overlaps the MFMAs;
        // runs max 2 past the end -> E2T padded)
        stage(gsrc0 + (size_t)(i + 2) * CHB, buf);

        f32x16 a1, a2;
#pragma unroll
        for (int r = 0; r < 16; ++r) { a1[r] = m2v; a2[r] = 0.f; }

        a1 = __builtin_amdgcn_mfma_f32_32x32x16_bf16(ah[0], Bh[0], a1, 0, 0, 0);
        a2 = __builtin_amdgcn_mfma_f32_32x32x16_bf16(ah[0], Bl[0], a2, 0, 0, 0);
        a1 = __builtin_amdgcn_mfma_f32_32x32x16_bf16(ah[1], Bh[1], a1, 0, 0, 0);
        a2 = __builtin_amdgcn_mfma_f32_32x32x16_bf16(ah[1], Bl[1], a2, 0, 0, 0);
        a1 = __builtin_amdgcn_mfma_f32_32x32x16_bf16(ah[2], Bh[2], a1, 0, 0, 0);
        a2 = __builtin_amdgcn_mfma_f32_32x32x16_bf16(ah[2], Bl[2], a2, 0, 0, 0);
        a1 = __builtin_amdgcn_mfma_f32_32x32x16_bf16(ah[3], Bh[3], a1, 0, 0, 0);
        a2 = __builtin_amdgcn_mfma_f32_32x32x16_bf16(ah[3], Bl[3], a2, 0, 0, 0);
        a1 = __builtin_amdgcn_mfma_f32_32x32x16_bf16(al[0], Bh[0], a1, 0, 0, 0);
        a1 = __builtin_amdgcn_mfma_f32_32x32x16_bf16(al[1], Bh[1], a1, 0, 0, 0);
        a1 = __builtin_amdgcn_mfma_f32_32x32x16_bf16(al[2], Bh[2], a1, 0, 0, 0);
        a1 = __builtin_amdgcn_mfma_f32_32x32x16_bf16(al[3], Bh[3], a1, 0, 0, 0);

        int cc = cbase + i * 32 + col;
#pragma unroll
        for (int r = 0; r < 16; ++r) {
            float s = a1[r] + a2[r];
            bv2[r] = __builtin_amdgcn_fmed3f(bv2[r], s, bv[r]);
            bool gt = s > bv[r];
            bi[r] = gt ? cc : bi[r];
            bv[r] = fmaxf(bv[r], s);
        }
    };

#pragma unroll 1
    for (int i = 0; i < 64; i += 2) {
        body(&lds[0][w][0], i);
        body(&lds[1][w][0], i + 1);
    }

    // ---- cross-col top-2 butterfly (32 cols; masks 1..16 keep kh) ----------
#pragma unroll
    for (int r = 0; r < 16; ++r) {
#pragma unroll
        for (int m = 1; m <= 16; m <<= 1) {
            float pv1 = __shfl_xor(bv[r],  m, 64);
            float pv2 = __shfl_xor(bv2[r], m, 64);
            int   pi  = __shfl_xor(bi[r],  m, 64);
            bool take = (pv1 > bv[r]) || (pv1 == bv[r] && pi < bi[r]);
            float lo1 = take ? bv[r] : pv1;
            bv2[r] = fmaxf(lo1, fmaxf(bv2[r], pv2));
            bv[r]  = take ? pv1 : bv[r];
            bi[r]  = take ? pi  : bi[r];
        }
    }
    if (col == 0) {                     // lanes 0 and 32
#pragma unroll
        for (int r = 0; r < 16; ++r) {
            int row = (r & 3) + 8 * (r >> 2) + 4 * kh;   // D-row = query
            sbv [w][row] = bv[r];
            sbv2[w][row] = bv2[r];
            sbi [w][row] = bi[r];
        }
    }
    __syncthreads();

    // ---- merge halves, flag small margins ----------------------------------
    if (tid < 32) {
        int q = tid;
        float bvA = sbv[0][q],  bvB = sbv[1][q];
        float b2A = sbv2[0][q], b2B = sbv2[1][q];
        bool  tb  = bvB > bvA;                    // tie -> half 0 (smaller c)
        float bvm  = tb ? bvB : bvA;
        int   bim  = tb ? sbi[1][q] : sbi[0][q];
        float bv2m = fmaxf(fmaxf(b2A, b2B), fminf(bvA, bvB));
        fin[q] = bim;
        if (bvm - bv2m < TAU) {
            int n = q0 + q;
            int slot = atomicAdd(wl_count, 1);
            if (slot < WLCAP) {
                wl[slot] = (h << 16) | n;
                packed[(h << 12) | n] = ~0ull;
            }
        }
    }
    __syncthreads();

    // ---- gather values[h, fin[q], :] -> out; 32 rows x 16 float4 -----------
#pragma unroll
    for (int k = 0; k < 4; ++k) {
        int f   = tid + k * 128;
        int row = f >> 4;
        int cl  = (f & 15) << 2;
        int idx = fin[row];
        float4 v = *reinterpret_cast<const float4*>(
            values + (size_t)h * CODES * DVI + (size_t)idx * DVI + cl);
        *reinterpret_cast<float4*>(
            out + (size_t)(q0 + row) * DIMX + h * DVI + cl) = v;
    }
}

// ---- pass 2a: numpy-bit-exact d2, 4 blocks per flagged query ---------------
// d2 > 0 always, so float bits are order-preserving: pack (d2_bits, c) into
// u64; atomicMin gives min d2 with first-index tie-breaking.
__global__ __launch_bounds__(256) void np_recheck(const float* __restrict__ x,
                                                  const float* __restrict__ ke,
                                                  const float* __restrict__ e2np,
                                                  const int* __restrict__ wl_count,
                                                  const int* __restrict__ wl,
                                                  u64* __restrict__ packed) {
    __shared__ float xs[DKI];
    __shared__ u64   sbest;

    const int tid = threadIdx.x;
    int cnt = *wl_count;
    if (cnt > WLCAP) cnt = WLCAP;
    int jobs = cnt * 4;

    for (int j = blockIdx.x; j < jobs; j += gridDim.x) {
        __syncthreads();                       // xs/sbest reuse guard
        int e = j >> 2, slice = j & 3;
        int ent = wl[e];
        int h = ent >> 16, nq = ent & 0xffff;
        if (tid < DKI) xs[tid] = x[(size_t)nq * DIMX + h * DKI + tid];
        if (tid == 0) sbest = ~0ull;
        __syncthreads();

        float x2 = np_sumsq64(xs);
        u64 lbest = ~0ull;
#pragma unroll 1
        for (int it = 0; it < 4; ++it) {
            int c = slice * 1024 + it * 256 + tid;   // ascending per thread
            float er[DKI];
            const float4* p = reinterpret_cast<const float4*>(
                ke + ((size_t)h * CODES + c) * DKI);
#pragma unroll
            for (int i = 0; i < DKI / 4; ++i) {
                float4 v = p[i];
                er[i * 4 + 0] = v.x; er[i * 4 + 1] = v.y;
                er[i * 4 + 2] = v.z; er[i * 4 + 3] = v.w;
            }
            float dot = np_dot64(xs, er);
            float d2;
            {
#pragma clang fp contract(off)
                d2 = (x2 - 2.0f * dot) + e2np[h * CODES + c];
            }
            u64 pk = ((u64)__float_as_uint(d2) << 32) | (unsigned)c;
            lbest = pk < lbest ? pk : lbest;
        }
        atomicMin(&sbest, lbest);
        __syncthreads();
        if (tid == 0) atomicMin(&packed[(h << 12) | nq], sbest);
    }
}

// ---- pass 2b: scatter corrected rows ---------------------------------------
__global__ __launch_bounds__(64) void np_scatter(const float* __restrict__ values,
                                                 const int* __restrict__ wl_count,
                                                 const int* __restrict__ wl,
                                                 const u64* __restrict__ packed,
                                                 float* __restrict__ out) {
    const int t = threadIdx.x;
    int cnt = *wl_count;
    if (cnt > WLCAP) cnt = WLCAP;
    for (int e = blockIdx.x; e < cnt; e += gridDim.x) {
        int ent = wl[e];
        int h = ent >> 16, nq = ent & 0xffff;
        int c = (int)(packed[(h << 12) | nq] & 0xffffffffull);
        out[(size_t)nq * DIMX + h * DVI + t] =
            values[((size_t)h * CODES + c) * DVI + t];
    }
}

extern "C" void kernel_launch(void* const* d_in, const int* in_sizes, int n_in,
                              void* d_out, int out_size, void* d_ws, size_t ws_size,
                              hipStream_t stream) {
    const float* x      = (const float*)d_in[0];
    // d_in[1] = mask (all ones; unused)
    const float* ke     = (const float*)d_in[2];
    const float* values = (const float*)d_in[3];
    // d_in[4] = key_optim (unused)
    float* out = (float*)d_out;

    char* ws = (char*)d_ws;
    float* e2np     = (float*)ws;  ws += HEADS * CODES * sizeof(float);
    int*   wl_count = (int*)ws;    ws += 16;
    int*   wl       = (int*)ws;    ws += WLCAP * sizeof(int);
    u64*   packed   = (u64*)ws;    ws += (size_t)HEADS * NTOK * sizeof(u64);
    char*  E2T      = ws;          // (1536 + 2 pad) chunks * 8448B ~ 13.0 MB

    prep_ke<<<dim3((HEADS * CODES + 255) / 256), dim3(256), 0, stream>>>(
        ke, E2T, e2np, wl_count);
    dkvb_mfma<<<dim3((NTOK / 32) * HEADS), dim3(128), 0, stream>>>(
        x, E2T, values, wl_count, wl, packed, out);
    np_recheck<<<dim3(4096), dim3(256), 0, stream>>>(
        x, ke, e2np, wl_count, wl, packed);
    np_scatter<<<dim3(2048), dim3(64), 0, stream>>>(
        values, wl_count, wl, packed, out);
}